// Round 10
// baseline (157.772 us; speedup 1.0000x reference)
//
#include <hip/hip_runtime.h>
#include <math.h>

// (B,C,H,W)=(8,512,32,32), L=1024, 32 groups, 8 heads, ch=64
#define BATCH   8
#define CCH     512
#define LL      1024
#define NHEADS  8
#define CHD     64
#define EPSV    1e-5f
#define QSCALE  0.1803368801111204f   // 0.125 / ln(2): folded into q so S is in log2 units

typedef __bf16 bf16_t;
typedef bf16_t bf16x8 __attribute__((ext_vector_type(8)));
typedef bf16_t bf16x4 __attribute__((ext_vector_type(4)));
typedef float  f32x4  __attribute__((ext_vector_type(4)));

__device__ __forceinline__ bf16_t f2b(float f) {
  unsigned u = __float_as_uint(f);
  u += 0x7fff + ((u >> 16) & 1);               // RNE
  return __builtin_bit_cast(bf16_t, (unsigned short)(u >> 16));
}

__device__ __forceinline__ unsigned pack2(float lo, float hi) {
  unsigned a = (unsigned)__builtin_bit_cast(unsigned short, f2b(lo));
  unsigned b = (unsigned)__builtin_bit_cast(unsigned short, f2b(hi));
  return (b << 16) | a;
}

__device__ __forceinline__ void gload_lds16(const void* g, void* l) {
  __builtin_amdgcn_global_load_lds(
      (const __attribute__((address_space(1))) void*)g,
      (__attribute__((address_space(3))) void*)l, 16, 0, 0);
}

// ---------------------------------------------------------------------------
// K1: fused prep.  Blocks 0..1023: fp32->bf16 weight convert (qkv_w + proj_w).
// Blocks 1024..1279: GroupNorm stats+normalize+affine+transpose -> xnT bf16.
// ---------------------------------------------------------------------------
__global__ __launch_bounds__(256) void prep_fused(const float* __restrict__ qkvw,
                                                  const float* __restrict__ projw,
                                                  bf16_t* __restrict__ wqb,
                                                  bf16_t* __restrict__ wpb,
                                                  const float* __restrict__ x,
                                                  const float* __restrict__ gsc,
                                                  const float* __restrict__ gbi,
                                                  bf16_t* __restrict__ xnT) {
  int bid = blockIdx.x;
  int tid = threadIdx.x;
  if (bid < 1024) {
    int i = (bid * 256 + tid) * 4;
    const float* src;
    bf16_t* dst;
    int j;
    if (i < 1536 * 512) { src = qkvw; dst = wqb; j = i; }
    else                { src = projw; dst = wpb; j = i - 1536 * 512; }
    float4 v = *(const float4*)(src + j);
    bf16x4 o = {f2b(v.x), f2b(v.y), f2b(v.z), f2b(v.w)};
    *(bf16x4*)(dst + j) = o;
    return;
  }
  int lin = bid - 1024;
  int xcd = lin & 7, slot = lin >> 3;
  int b = slot & 7, jj = slot >> 3;
  int g = xcd * 4 + jj;
  const float4* x4 = (const float4*)(x + ((size_t)(b * 32 + g)) * 16 * LL);

  float s = 0.f, ss = 0.f;
  float4 v[16];
#pragma unroll
  for (int it = 0; it < 16; ++it) {
    float4 f = x4[it * 256 + tid];
    v[it] = f;
    s += f.x + f.y + f.z + f.w;
    ss += f.x * f.x + f.y * f.y + f.z * f.z + f.w * f.w;
  }
#pragma unroll
  for (int m = 1; m < 64; m <<= 1) { s += __shfl_xor(s, m); ss += __shfl_xor(ss, m); }
  __shared__ float rs_[4], rss[4];
  int wv = tid >> 6, ln = tid & 63;
  if (ln == 0) { rs_[wv] = s; rss[wv] = ss; }
  __syncthreads();
  s  = rs_[0] + rs_[1] + rs_[2] + rs_[3];
  ss = rss[0] + rss[1] + rss[2] + rss[3];
  float mean = s * (1.f / 16384.f);
  float var  = ss * (1.f / 16384.f) - mean * mean;
  float rstd = rsqrtf(var + EPSV);

  float sc[16], bi[16];
#pragma unroll
  for (int it = 0; it < 16; ++it) {
    sc[it] = gsc[g * 16 + it] * rstd;
    bi[it] = gbi[g * 16 + it] - mean * sc[it];
  }

#pragma unroll
  for (int j = 0; j < 4; ++j) {
    unsigned w[8];
#pragma unroll
    for (int k = 0; k < 8; ++k) {
      float a0 = (j == 0 ? v[2 * k].x : j == 1 ? v[2 * k].y : j == 2 ? v[2 * k].z : v[2 * k].w);
      float a1 = (j == 0 ? v[2 * k + 1].x : j == 1 ? v[2 * k + 1].y : j == 2 ? v[2 * k + 1].z : v[2 * k + 1].w);
      w[k] = pack2(a0 * sc[2 * k] + bi[2 * k], a1 * sc[2 * k + 1] + bi[2 * k + 1]);
    }
    int l = tid * 4 + j;
    bf16_t* dst = xnT + ((size_t)b * LL + l) * CCH + g * 16;
    *(uint4*)dst = make_uint4(w[0], w[1], w[2], w[3]);
    *(uint4*)(dst + 8) = make_uint4(w[4], w[5], w[6], w[7]);
  }
}

// ---------------------------------------------------------------------------
// K2: qkv GEMM (MFMA).  128x256 block tile, BK=64; wave tile 64x128 (4m x 8n).
// Grid (x=b, y=ot(12), z=lt(4)) so linear%8 == b (XCD/L2 locality).
// global_load_lds w16, XOR-granule swizzle on the global source.
// Epilogue: b64 packed stores; q scaled by QSCALE; v transposed+s-permuted.
// ---------------------------------------------------------------------------
__global__ __launch_bounds__(256, 2) void qkv_mfma(const bf16_t* __restrict__ wq,
                                                   const bf16_t* __restrict__ xnT,
                                                   const float* __restrict__ qkvb,
                                                   bf16_t* __restrict__ qt,
                                                   bf16_t* __restrict__ kt,
                                                   bf16_t* __restrict__ vt) {
  __shared__ bf16_t As[128 * 64];
  __shared__ bf16_t Bs[256 * 64];
  int tid = threadIdx.x;
  int wave = tid >> 6, lane = tid & 63;
  int lrow = lane & 15, quad = lane >> 4;
  int wm = wave >> 1, wn = wave & 1;
  int b = blockIdx.x;
  int oBase = blockIdx.y * 128, lBase = blockIdx.z * 256;
  int srow = lane >> 3;
  int sgOff = (((lane & 7) ^ srow) << 4);

  f32x4 acc[4][8] = {};
  for (int ktile = 0; ktile < 8; ++ktile) {
    int kB = ktile * 64;
    __syncthreads();
#pragma unroll
    for (int j = 0; j < 4; ++j) {
      int ci = wave * 4 + j;
      int R = ci * 8 + srow;
      gload_lds16((const char*)(wq + (size_t)(oBase + R) * CCH + kB) + sgOff,
                  (char*)As + ci * 1024);
    }
#pragma unroll
    for (int j = 0; j < 8; ++j) {
      int ci = wave * 8 + j;
      int R = ci * 8 + srow;
      gload_lds16((const char*)(xnT + ((size_t)b * LL + lBase + R) * CCH + kB) + sgOff,
                  (char*)Bs + ci * 1024);
    }
    __syncthreads();
#pragma unroll
    for (int kk = 0; kk < 2; ++kk) {
      int g = (kk * 4 + quad) ^ (lrow & 7);
      bf16x8 af[4], bfr[8];
#pragma unroll
      for (int m = 0; m < 4; ++m) {
        int r = wm * 64 + m * 16 + lrow;
        af[m] = *(const bf16x8*)(As + r * 64 + g * 8);
      }
#pragma unroll
      for (int n = 0; n < 8; ++n) {
        int r = wn * 128 + n * 16 + lrow;
        bfr[n] = *(const bf16x8*)(Bs + r * 64 + g * 8);
      }
#pragma unroll
      for (int m = 0; m < 4; ++m)
#pragma unroll
        for (int n = 0; n < 8; ++n)
          acc[m][n] = __builtin_amdgcn_mfma_f32_16x16x32_bf16(af[m], bfr[n], acc[m][n], 0, 0, 0);
    }
  }

  int oW = oBase + wm * 64;
  int lW = lBase + wn * 128;
  int sec = oW >> 9;
#pragma unroll
  for (int m = 0; m < 4; ++m) {
    int o4 = oW + m * 16 + quad * 4;
    float4 bb4 = *(const float4*)&qkvb[o4];
    int cc = o4 & 511;
    int head = cc >> 6, ch = cc & 63;
    int bh = b * NHEADS + head;
    if (sec == 0) {
#pragma unroll
      for (int n = 0; n < 8; ++n) {
        int l = lW + n * 16 + lrow;
        unsigned d0 = pack2((acc[m][n][0] + bb4.x) * QSCALE,
                            (acc[m][n][1] + bb4.y) * QSCALE);
        unsigned d1 = pack2((acc[m][n][2] + bb4.z) * QSCALE,
                            (acc[m][n][3] + bb4.w) * QSCALE);
        *(uint2*)(qt + ((size_t)bh * LL + l) * CHD + ch) = make_uint2(d0, d1);
      }
    } else if (sec == 1) {
#pragma unroll
      for (int n = 0; n < 8; ++n) {
        int l = lW + n * 16 + lrow;
        unsigned d0 = pack2(acc[m][n][0] + bb4.x, acc[m][n][1] + bb4.y);
        unsigned d1 = pack2(acc[m][n][2] + bb4.z, acc[m][n][3] + bb4.w);
        *(uint2*)(kt + ((size_t)bh * LL + l) * CHD + ch) = make_uint2(d0, d1);
      }
    } else {
      float bb[4] = {bb4.x, bb4.y, bb4.z, bb4.w};
#pragma unroll
      for (int c = 0; c < 2; ++c) {
#pragma unroll
        for (int i = 0; i < 4; ++i) {
          unsigned d0 = pack2(acc[m][c * 4 + 0][i] + bb[i], acc[m][c * 4 + 1][i] + bb[i]);
          unsigned d1 = pack2(acc[m][c * 4 + 2][i] + bb[i], acc[m][c * 4 + 3][i] + bb[i]);
          *(uint2*)(vt + ((size_t)bh * CHD + ch + i) * LL + lW + c * 64 + lrow * 4) =
              make_uint2(d0, d1);
        }
      }
    }
  }
}

// ---------------------------------------------------------------------------
// K3: flash attention (MFMA), no-max softmax in log2 units.
// NEW: wave owns 64 q-rows (4 subtiles h) -> each K/V LDS fragment feeds 4x
// the MFMA work (DS per unit work ~2/3 of the 32-row version; matrix pipe
// becomes the top term).  Block = 256 rows, grid (x=bh 64, y=tt 4) = 1/CU;
// linear%8 == bh%8 keeps K/V per-XCD.  K/V double-buffered via
// global_load_lds w16 + XOR-granule swizzle; K frags cached in regs per tile;
// P per (wave,h) in stride-64 LDS with XOR-granule swizzle (write granule
// (lrow>>1)^(t&7), reads use the same swz0/swz1 as kbuf -> conflict-free).
// LDS = 16+16+32 = 64 KB exactly.  exp2-only softmax; row-sum via ones-MFMA.
// ---------------------------------------------------------------------------
__global__ __launch_bounds__(256, 1) void attn_mfma(const bf16_t* __restrict__ qt,
                                                    const bf16_t* __restrict__ kt,
                                                    const bf16_t* __restrict__ vt,
                                                    bf16_t* __restrict__ at) {
  __shared__ bf16_t kbuf[2][64 * 64];
  __shared__ bf16_t vbuf[2][64 * 64];
  __shared__ bf16_t pb[4 * 4 * 16 * 64];        // [wave][h][16 t][64 s-els]
  int tid = threadIdx.x, wave = tid >> 6, lane = tid & 63;
  int lrow = lane & 15, quad = lane >> 4;
  int bh = blockIdx.x;
  int tW = blockIdx.y * 256 + wave * 64;
  const bf16_t* qb = qt + (size_t)bh * LL * CHD;
  const bf16_t* kb = kt + (size_t)bh * LL * CHD;
  const bf16_t* vb = vt + (size_t)bh * CHD * LL;

  int srow = lane >> 3;
  int sgb = (((lane & 7) ^ srow) << 4);

  bf16x8 qf[4][2];
#pragma unroll
  for (int h = 0; h < 4; ++h) {
    const bf16_t* qp = qb + (size_t)(tW + h * 16 + lrow) * CHD + quad * 8;
    qf[h][0] = *(const bf16x8*)qp;
    qf[h][1] = *(const bf16x8*)(qp + 32);
  }

  bf16x8 ones;
#pragma unroll
  for (int j = 0; j < 8; ++j) ones[j] = (bf16_t)1.0f;

  f32x4 Oa[4][4] = {};
  f32x4 Os[4] = {};

  // stage tile 0 (8 K-chunks + 8 V-chunks over 4 waves)
#pragma unroll
  for (int j = 0; j < 2; ++j) {
    int c = wave * 2 + j;
    int R = c * 8 + srow;
    gload_lds16((const char*)(kb + (size_t)R * CHD) + sgb, (char*)&kbuf[0][0] + c * 1024);
    gload_lds16((const char*)(vb + (size_t)R * LL) + sgb, (char*)&vbuf[0][0] + c * 1024);
  }
  __syncthreads();

  int swz0 = (quad ^ (lrow & 7)) * 8;
  int swz1 = ((quad + 4) ^ (lrow & 7)) * 8;

  for (int st = 0; st < 16; ++st) {
    int cur = st & 1;
    if (st < 15) {
      int sBn = (st + 1) * 64;
#pragma unroll
      for (int j = 0; j < 2; ++j) {
        int c = wave * 2 + j;
        int R = c * 8 + srow;
        gload_lds16((const char*)(kb + (size_t)(sBn + R) * CHD) + sgb,
                    (char*)&kbuf[cur ^ 1][0] + c * 1024);
        gload_lds16((const char*)(vb + (size_t)R * LL + sBn) + sgb,
                    (char*)&vbuf[cur ^ 1][0] + c * 1024);
      }
    }
    const bf16_t* kbase = &kbuf[cur][0];
    const bf16_t* vbase = &vbuf[cur][0];

    // K fragments once per tile, reused by all 4 h-subtiles
    bf16x8 kf0[4], kf1[4];
#pragma unroll
    for (int ss = 0; ss < 4; ++ss) {
      int s = ss * 16 + lrow;
      kf0[ss] = *(const bf16x8*)(kbase + s * 64 + swz0);
      kf1[ss] = *(const bf16x8*)(kbase + s * 64 + swz1);
    }

    // per-h: QK^T -> exp2 -> pack -> P store (stride-64, XOR-swizzled)
#pragma unroll
    for (int h = 0; h < 4; ++h) {
      f32x4 S[4];
#pragma unroll
      for (int ss = 0; ss < 4; ++ss) {
        f32x4 z = {0.f, 0.f, 0.f, 0.f};
        z = __builtin_amdgcn_mfma_f32_16x16x32_bf16(qf[h][0], kf0[ss], z, 0, 0, 0);
        S[ss] = __builtin_amdgcn_mfma_f32_16x16x32_bf16(qf[h][1], kf1[ss], z, 0, 0, 0);
      }
      float p[4][4];
#pragma unroll
      for (int ss = 0; ss < 4; ++ss)
#pragma unroll
        for (int i = 0; i < 4; ++i)
          p[ss][i] = __builtin_amdgcn_exp2f(S[ss][i]);
      bf16_t* pw = pb + (wave * 4 + h) * 1024;
#pragma unroll
      for (int i = 0; i < 4; ++i) {
        int t = quad * 4 + i;
        unsigned d0 = __builtin_amdgcn_perm(__float_as_uint(p[1][i]),
                                            __float_as_uint(p[0][i]), 0x07060302u);
        unsigned d1 = __builtin_amdgcn_perm(__float_as_uint(p[3][i]),
                                            __float_as_uint(p[2][i]), 0x07060302u);
        int off = t * 64 + ((((lrow >> 1) ^ (t & 7)) << 3) | ((lrow & 1) << 2));
        *(uint2*)(pw + off) = make_uint2(d0, d1);
      }
    }
    asm volatile("s_waitcnt lgkmcnt(0)" ::: "memory");   // wave-private P

    bf16x8 pf0[4], pf1[4];
#pragma unroll
    for (int h = 0; h < 4; ++h) {
      const bf16_t* pw = pb + (wave * 4 + h) * 1024;
      pf0[h] = *(const bf16x8*)(pw + lrow * 64 + swz0);
      pf1[h] = *(const bf16x8*)(pw + lrow * 64 + swz1);
    }

    // PV: V fragments read once per tile, reused by all 4 h
#pragma unroll
    for (int n = 0; n < 4; ++n) {
      int r = (n * 16 + lrow) * 64;
      bf16x8 v0 = *(const bf16x8*)(vbase + r + swz0);
      bf16x8 v1 = *(const bf16x8*)(vbase + r + swz1);
#pragma unroll
      for (int h = 0; h < 4; ++h) {
        Oa[h][n] = __builtin_amdgcn_mfma_f32_16x16x32_bf16(pf0[h], v0, Oa[h][n], 0, 0, 0);
        Oa[h][n] = __builtin_amdgcn_mfma_f32_16x16x32_bf16(pf1[h], v1, Oa[h][n], 0, 0, 0);
      }
    }
#pragma unroll
    for (int h = 0; h < 4; ++h) {
      Os[h] = __builtin_amdgcn_mfma_f32_16x16x32_bf16(pf0[h], ones, Os[h], 0, 0, 0);
      Os[h] = __builtin_amdgcn_mfma_f32_16x16x32_bf16(pf1[h], ones, Os[h], 0, 0, 0);
    }

    __syncthreads();   // staged tile st+1 landed; all waves done with buf[cur]
  }

  bf16_t* ab = at + (size_t)bh * LL * CHD;
#pragma unroll
  for (int h = 0; h < 4; ++h) {
    float inv[4];
#pragma unroll
    for (int i = 0; i < 4; ++i) inv[i] = 1.f / Os[h][i];
#pragma unroll
    for (int n = 0; n < 4; ++n)
#pragma unroll
      for (int i = 0; i < 4; ++i)
        ab[(size_t)(tW + h * 16 + quad * 4 + i) * CHD + n * 16 + lrow] =
            f2b(Oa[h][n][i] * inv[i]);
  }
}

// ---------------------------------------------------------------------------
// K4: proj GEMM (MFMA) + bias + fp32 residual, LDS-staged.
// BK=64 == one head of at.  Grid (x=b, y=ot, z=lt), linear%8 == b.
// ---------------------------------------------------------------------------
__global__ __launch_bounds__(256) void proj_mfma(const bf16_t* __restrict__ wp,
                                                 const bf16_t* __restrict__ at,
                                                 const float* __restrict__ projb,
                                                 const float* __restrict__ x,
                                                 float* __restrict__ out) {
  __shared__ bf16_t As[128 * 64];
  __shared__ bf16_t Bs[128 * 64];
  int tid = threadIdx.x;
  int wave = tid >> 6, lane = tid & 63;
  int lrow = lane & 15, quad = lane >> 4;
  int wm = wave >> 1, wn = wave & 1;
  int b = blockIdx.x;
  int oBase = blockIdx.y * 128, lBase = blockIdx.z * 128;
  int srow = lane >> 3;
  int sgOff = (((lane & 7) ^ srow) << 4);

  f32x4 acc[4][4] = {};
  for (int ktile = 0; ktile < 8; ++ktile) {     // head = ktile
    int kB = ktile * 64;
    __syncthreads();
#pragma unroll
    for (int j = 0; j < 4; ++j) {
      int ci = wave * 4 + j;
      int R = ci * 8 + srow;
      gload_lds16((const char*)(wp + (size_t)(oBase + R) * CCH + kB) + sgOff,
                  (char*)As + ci * 1024);
      gload_lds16((const char*)(at + ((size_t)(b * NHEADS + ktile) * LL + lBase + R) * CHD) + sgOff,
                  (char*)Bs + ci * 1024);
    }
    __syncthreads();
#pragma unroll
    for (int kk = 0; kk < 2; ++kk) {
      int g = (kk * 4 + quad) ^ (lrow & 7);
      bf16x8 af[4], bfr[4];
#pragma unroll
      for (int m = 0; m < 4; ++m) {
        int r = wm * 64 + m * 16 + lrow;
        af[m] = *(const bf16x8*)(As + r * 64 + g * 8);
      }
#pragma unroll
      for (int n = 0; n < 4; ++n) {
        int r = wn * 64 + n * 16 + lrow;
        bfr[n] = *(const bf16x8*)(Bs + r * 64 + g * 8);
      }
#pragma unroll
      for (int m = 0; m < 4; ++m)
#pragma unroll
        for (int n = 0; n < 4; ++n)
          acc[m][n] = __builtin_amdgcn_mfma_f32_16x16x32_bf16(af[m], bfr[n], acc[m][n], 0, 0, 0);
    }
  }

  int oW = oBase + wm * 64;
  int lW = lBase + wn * 64;
#pragma unroll
  for (int m = 0; m < 4; ++m) {
#pragma unroll
    for (int i = 0; i < 4; ++i) {
      int o = oW + m * 16 + quad * 4 + i;
      float bb = projb[o];
#pragma unroll
      for (int n = 0; n < 4; ++n) {
        int l = lW + n * 16 + lrow;
        size_t off = ((size_t)(b * CCH + o)) * LL + l;
        out[off] = acc[m][n][i] + bb + x[off];
      }
    }
  }
}

// ---------------------------------------------------------------------------
extern "C" void kernel_launch(void* const* d_in, const int* in_sizes, int n_in,
                              void* d_out, int out_size, void* d_ws, size_t ws_size,
                              hipStream_t stream) {
  const float* x     = (const float*)d_in[0];
  const float* gsc   = (const float*)d_in[1];
  const float* gbi   = (const float*)d_in[2];
  const float* qkvw  = (const float*)d_in[3];
  const float* qkvb  = (const float*)d_in[4];
  const float* projw = (const float*)d_in[5];
  const float* projb = (const float*)d_in[6];
  float* out = (float*)d_out;

  char* ws = (char*)d_ws;
  bf16_t* wqb   = (bf16_t*)(ws + 4096);
  bf16_t* wpb   = (bf16_t*)(ws + 4096 + 1572864);
  bf16_t* xnT   = (bf16_t*)(ws + 2101248);
  bf16_t* qt    = (bf16_t*)(ws + 2101248 + 8388608);
  bf16_t* kt    = (bf16_t*)(ws + 2101248 + 2 * 8388608);
  bf16_t* vt    = (bf16_t*)(ws + 2101248 + 3 * 8388608);
  bf16_t* at    = (bf16_t*)(ws + 2101248 + 4 * 8388608);

  hipLaunchKernelGGL(prep_fused, dim3(1280), dim3(256), 0, stream,
                     qkvw, projw, wqb, wpb, x, gsc, gbi, xnT);
  hipLaunchKernelGGL(qkv_mfma, dim3(BATCH, 12, 4), dim3(256), 0, stream,
                     wqb, xnT, qkvb, qt, kt, vt);
  hipLaunchKernelGGL(attn_mfma, dim3(64, 4), dim3(256), 0, stream, qt, kt, vt, at);
  hipLaunchKernelGGL(proj_mfma, dim3(BATCH, 4, 8), dim3(256), 0, stream,
                     wpb, at, projb, x, out);
}